// Round 5
// baseline (2044.414 us; speedup 1.0000x reference)
//
#include <hip/hip_runtime.h>
#include <hip/hip_bf16.h>

#define K_ITEMS 50
#define N_PAIRS 1225   // K*(K-1)/2
#define N_COLS  20000
#define FULL_ITERS (N_PAIRS / 256)   // 4
#define TAIL_BASE  (FULL_ITERS * 256) // 1024

// Compile-time LUT: pair p -> (i<<8)|j for i<j, i-major order
// (matches jnp.triu_indices(K, k=1)).
struct PairLUT {
    unsigned short v[N_PAIRS];
    constexpr PairLUT() : v() {
        int p = 0;
        for (int i = 0; i < K_ITEMS; ++i)
            for (int j = i + 1; j < K_ITEMS; ++j)
                v[p++] = (unsigned short)((i << 8) | j);
    }
};
__device__ constexpr PairLUT g_pairs{};

__global__ void __launch_bounds__(256)
ild_pair_sum_kernel(const int* __restrict__ rec,
                    const float* __restrict__ dm,
                    float* __restrict__ partial) {
    const int u = blockIdx.x;

    __shared__ int r[K_ITEMS];
    __shared__ unsigned short pl[N_PAIRS];

    if (threadIdx.x < K_ITEMS) r[threadIdx.x] = rec[u * K_ITEMS + threadIdx.x];
    for (int p = threadIdx.x; p < N_PAIRS; p += 256) pl[p] = g_pairs.v[p];
    __syncthreads();

    // 4 guaranteed-full iterations: issue 4 independent gathers back-to-back
    // (max memory-level parallelism per thread), then one predicated tail.
    float v[FULL_ITERS];
    #pragma unroll
    for (int it = 0; it < FULL_ITERS; ++it) {
        const int p = it * 256 + threadIdx.x;
        const unsigned short ij = pl[p];
        v[it] = dm[(size_t)r[ij >> 8] * N_COLS + (size_t)r[ij & 0xff]];
    }
    float acc = 0.f;
    {
        const int p = TAIL_BASE + threadIdx.x;
        if (p < N_PAIRS) {
            const unsigned short ij = pl[p];
            acc = dm[(size_t)r[ij >> 8] * N_COLS + (size_t)r[ij & 0xff]];
        }
    }
    #pragma unroll
    for (int it = 0; it < FULL_ITERS; ++it) acc += v[it];

    // wave reduce (64 lanes)
    #pragma unroll
    for (int off = 32; off > 0; off >>= 1)
        acc += __shfl_down(acc, off, 64);

    __shared__ float wred[4];
    const int lane = threadIdx.x & 63;
    const int wid  = threadIdx.x >> 6;
    if (lane == 0) wred[wid] = acc;
    __syncthreads();
    if (threadIdx.x == 0)
        partial[u] = wred[0] + wred[1] + wred[2] + wred[3];
}

__global__ void __launch_bounds__(1024)
ild_reduce_kernel(const float* __restrict__ partial, float* __restrict__ out, int n) {
    double acc = 0.0;
    for (int t = threadIdx.x; t < n; t += 1024)
        acc += (double)partial[t];

    #pragma unroll
    for (int off = 32; off > 0; off >>= 1)
        acc += __shfl_down(acc, off, 64);

    __shared__ double wred[16];
    const int lane = threadIdx.x & 63;
    const int wid  = threadIdx.x >> 6;
    if (lane == 0) wred[wid] = acc;
    __syncthreads();
    if (threadIdx.x == 0) {
        double total = 0.0;
        #pragma unroll
        for (int w = 0; w < 16; ++w) total += wred[w];
        const double denom = (double)(K_ITEMS * (K_ITEMS - 1)) * (double)n;
        out[0] = (float)(total / denom);
    }
}

extern "C" void kernel_launch(void* const* d_in, const int* in_sizes, int n_in,
                              void* d_out, int out_size, void* d_ws, size_t ws_size,
                              hipStream_t stream) {
    const int*   rec = (const int*)d_in[0];
    const float* dm  = (const float*)d_in[1];
    float* out       = (float*)d_out;

    const int B = in_sizes[0] / K_ITEMS;   // 16384 users
    float* partial = (float*)d_ws;          // B floats of scratch

    ild_pair_sum_kernel<<<B, 256, 0, stream>>>(rec, dm, partial);
    ild_reduce_kernel<<<1, 1024, 0, stream>>>(partial, out, B);
}